// Round 6
// baseline (239.612 us; speedup 1.0000x reference)
//
#include <hip/hip_runtime.h>
#include <hip/hip_bf16.h>
#include <stdint.h>

// ---------------------------------------------------------------------------
// PiCO forward: B=4096, D_IN=1024, LOW_DIM=128, NUM_CLASS=32, MOCO_QUEUE=65536
// Round 6: overlap the BW-bound queue copies with the latency-bound GEMM in
// ONE launch (gemm blocks first, copy blocks stream behind). Barrier-free
// K-loop kept from R5; unroll deepened to 8. 3 launches total.
// ---------------------------------------------------------------------------

typedef __attribute__((ext_vector_type(8))) short bf16x8;
typedef __attribute__((ext_vector_type(4))) float f32x4;

// output offsets (in floats), concatenated in reference return order
constexpr size_t O0 = 0;          // output            (4096,32)
constexpr size_t O1 = 131072;     // features          (73728,128)
constexpr size_t O2 = 9568256;    // pseudo_scores     (73728,32)
constexpr size_t O3 = 11927552;   // partial_target    (73728,32)
constexpr size_t O4 = 14286848;   // score_prot        (4096,32)
constexpr size_t O5 = 14417920;   // new_protos        (32,128)
constexpr size_t O6 = 14422016;   // new_queue         (65536,128)
constexpr size_t O7 = 22810624;   // new_queue_pseudo  (65536,32)
constexpr size_t O8 = 24907776;   // new_queue_partial (65536,32)

__device__ __forceinline__ unsigned short f2b(float x) {
  union { float f; uint32_t u; } v; v.f = x;
  uint32_t u = v.u;
  uint32_t r = (u + 0x7fffu + ((u >> 16) & 1u)) >> 16;   // RNE f32->bf16
  return (unsigned short)r;
}

// ---------------------------------------------------------------------------
// prep: 3 weight transposes into bf16 [N][1024].
// ---------------------------------------------------------------------------
__global__ __launch_bounds__(256) void prep(
    const float* __restrict__ Wpq, const float* __restrict__ Wcq,
    const float* __restrict__ Wpk,
    unsigned short* __restrict__ wt_q, unsigned short* __restrict__ wt_pk) {
  const int bid = blockIdx.x;
  const int t = threadIdx.x;
  const float *W1, *W2 = nullptr;
  float a1 = 1.f, a2 = 0.f;
  unsigned short* dst;
  int kb, nbr, nbw, N;
  if (bid < 128) {
    W1 = Wpq; N = 128; kb = (bid & 31) * 32; nbr = nbw = (bid >> 5) * 32;
    dst = wt_q;
  } else if (bid < 160) {
    W1 = Wcq; N = 32; kb = (bid - 128) * 32; nbr = 0; nbw = 128; dst = wt_q;
  } else {
    W1 = Wpk; W2 = Wpq; a1 = 0.999f; a2 = 0.001f; N = 128;
    const int b = bid - 160; kb = (b & 31) * 32; nbr = nbw = (b >> 5) * 32;
    dst = wt_pk;
  }
  __shared__ float tile[32][33];
  const int tx = t & 31, ty = t >> 5;
#pragma unroll
  for (int j = 0; j < 4; ++j) {
    const int k = kb + ty + 8 * j;
    float v = W1[(size_t)k * N + nbr + tx] * a1;
    if (W2) v += W2[(size_t)k * N + nbr + tx] * a2;
    tile[ty + 8 * j][tx] = v;
  }
  __syncthreads();
#pragma unroll
  for (int j = 0; j < 4; ++j) {
    const int n = nbw + ty + 8 * j;
    dst[(size_t)n * 1024 + kb + tx] = f2b(tile[tx][ty + 8 * j]);
  }
}

// ---------------------------------------------------------------------------
// mega: 3584 blocks x 320 threads.
//  bid [0,256)     : q-path GEMM (BM=16 x BN=160) + full q epilogue
//  bid [256,512)   : k-path GEMM (BM=16 x BN=128) + l2norm epilogue
//  bid [512,3584)  : queue copies (grid-stride, BW-bound) — overlap the
//                    latency-bound gemm blocks on the same CUs.
// ---------------------------------------------------------------------------
__global__ __launch_bounds__(320) void mega(
    const float* __restrict__ img_q, const float* __restrict__ im_k,
    const unsigned short* __restrict__ wt_q,
    const unsigned short* __restrict__ wt_pk,
    const float* __restrict__ bias, const float* __restrict__ partialY,
    const float* __restrict__ protos, const float* __restrict__ queue,
    const float* __restrict__ qp, const float* __restrict__ qpt,
    float* __restrict__ out, int* __restrict__ labels) {
  __shared__ __align__(16) unsigned char smem[32768];
  const int bid = blockIdx.x;
  const int t = threadIdx.x;

  if (bid >= 512) {  // ---- copy path: 141 MB of queue concat + requeue ----
    constexpr long NQ4 = (long)65536 * 128 / 4;   // 2097152
    constexpr long NP4 = (long)65536 * 32 / 4;    // 524288
    constexpr long TOT = NQ4 + 2 * NP4;           // 3145728
    float4* o4 = (float4*)out;
    for (long idx = (long)(bid - 512) * 320 + t; idx < TOT; idx += 3072L * 320) {
      if (idx < NQ4) {
        const float4 v = ((const float4*)queue)[idx];
        o4[O1 / 4 + (2L * 4096 * 128) / 4 + idx] = v;
        if ((idx >> 5) >= 4096) o4[O6 / 4 + idx] = v;
      } else if (idx < NQ4 + NP4) {
        const long i = idx - NQ4;
        const float4 v = ((const float4*)qp)[i];
        o4[O2 / 4 + (2L * 4096 * 32) / 4 + i] = v;
        if ((i >> 3) >= 4096) o4[O7 / 4 + i] = v;
      } else {
        const long i = idx - NQ4 - NP4;
        const float4 v = ((const float4*)qpt)[i];
        o4[O3 / 4 + (2L * 4096 * 32) / 4 + i] = v;
        if ((i >> 3) >= 4096) o4[O8 / 4 + i] = v;
      }
    }
    return;
  }

  // ---- GEMM paths ----
  const int w = t >> 6, l = t & 63;
  const int ar = l & 15, kg = l >> 4;
  const bool isq = bid < 256;
  const int m0 = (isq ? bid : bid - 256) * 16;
  const float* A = isq ? img_q : im_k;
  const unsigned short* Wt = isq ? wt_q : wt_pk;
  const int nstrips = isq ? 5 : 4;

  // stage A once: 16 rows x 1024 f32 -> bf16, XOR-swizzled (row*2048 base)
  if (t < 256) {
    const int r = t >> 4, cb = (t & 15) * 4;
    const float* ap = A + (size_t)(m0 + r) * 1024;
    const int sw = (r & 7) << 4;
#pragma unroll
    for (int j = 0; j < 16; ++j) {
      const int col = cb + j * 64;
      const float4 v = *(const float4*)(ap + col);
      uint2 pk;
      pk.x = (uint32_t)f2b(v.x) | ((uint32_t)f2b(v.y) << 16);
      pk.y = (uint32_t)f2b(v.z) | ((uint32_t)f2b(v.w) << 16);
      *(uint2*)(smem + r * 2048 + ((col * 2) ^ sw)) = pk;
    }
  }
  __syncthreads();

  // barrier-free K-loop: A from LDS, B from global (L2-hot weights)
  f32x4 acc0 = {0.f, 0.f, 0.f, 0.f}, acc1 = {0.f, 0.f, 0.f, 0.f};
  if (w < nstrips) {
    const int cs = w * 32;
    const unsigned short* b0p = Wt + (size_t)(cs + ar) * 1024;
    const unsigned short* b1p = Wt + (size_t)(cs + 16 + ar) * 1024;
    const int abase = ar * 2048;
    const int asw = (ar & 7) << 4;
#pragma unroll 8
    for (int kk = 0; kk < 32; ++kk) {
      const int k0 = kk * 32 + kg * 8;
      bf16x8 a = *(const bf16x8*)(smem + abase + ((k0 * 2) ^ asw));
      bf16x8 b0 = *(const bf16x8*)(b0p + k0);
      bf16x8 b1 = *(const bf16x8*)(b1p + k0);
      acc0 = __builtin_amdgcn_mfma_f32_16x16x32_bf16(a, b0, acc0, 0, 0, 0);
      acc1 = __builtin_amdgcn_mfma_f32_16x16x32_bf16(a, b1, acc1, 0, 0, 0);
    }
  }
  __syncthreads();  // all waves done reading sA; safe to overlay pr/Crow

  // epilogue: acc -> LDS row buffer; protos -> LDS (q only)
  float* pr = (float*)smem;                   // 32*129 f32 = 16504 B
  float* Crow = (float*)(smem + 16512);       // 16 x 164 f32 = 10496 B
  if (w < nstrips) {
#pragma unroll
    for (int j = 0; j < 4; ++j) {
      Crow[(kg * 4 + j) * 164 + w * 32 + ar] = acc0[j];
      Crow[(kg * 4 + j) * 164 + w * 32 + 16 + ar] = acc1[j];
    }
  }
  if (isq) {
    for (int i = t; i < 4096; i += 320)
      pr[(i >> 7) * 129 + (i & 127)] = protos[i];
  }
  __syncthreads();

  if (isq) {
    for (int r = w; r < 16; r += 5) {
      const int grow = m0 + r;
      const float* cr = Crow + r * 164;
      // logits + bias -> softmax -> * partial_Y
      float logit = -1e30f;
      if (l < 32) logit = cr[128 + l] + bias[l];
      float m = logit;
      for (int o = 32; o; o >>= 1) m = fmaxf(m, __shfl_xor(m, o));
      const float e = (l < 32) ? __expf(logit - m) : 0.f;
      float ssum = e;
      for (int o = 32; o; o >>= 1) ssum += __shfl_xor(ssum, o);
      const float py = (l < 32) ? partialY[(size_t)grow * 32 + l] : 0.f;
      const float p = e / ssum * py;
      if (l < 32) {
        out[O0 + (size_t)grow * 32 + l] = logit;
        out[O2 + (size_t)grow * 32 + l] = p;
        out[O2 + (size_t)(4096 + grow) * 32 + l] = p;
        out[O7 + (size_t)grow * 32 + l] = p;
        out[O3 + (size_t)grow * 32 + l] = py;
        out[O3 + (size_t)(4096 + grow) * 32 + l] = py;
        out[O8 + (size_t)grow * 32 + l] = py;
      }
      // argmax (first-index-wins)
      float av = (l < 32) ? p : -1.f;
      int ai = (l < 32) ? l : 1000;
      for (int o = 32; o; o >>= 1) {
        const float ov = __shfl_xor(av, o);
        const int oi = __shfl_xor(ai, o);
        if (ov > av || (ov == av && oi < ai)) { av = ov; ai = oi; }
      }
      if (l == 0) labels[grow] = ai;
      // l2norm(q) -> features + normalized row back to LDS (same wave)
      float v0 = cr[l], v1 = cr[64 + l];
      float ss = v0 * v0 + v1 * v1;
      for (int o = 32; o; o >>= 1) ss += __shfl_xor(ss, o);
      const float den = fmaxf(sqrtf(ss), 1e-12f);
      v0 /= den; v1 /= den;
      out[O1 + (size_t)grow * 128 + l] = v0;
      out[O1 + (size_t)grow * 128 + 64 + l] = v1;
      Crow[r * 164 + l] = v0;
      Crow[r * 164 + 64 + l] = v1;   // same-wave LDS RAW: lockstep-safe
      // score_prot = softmax(qn @ protos^T): lane pair (l,l+32), class l&31
      const int c = l & 31;
      const int dh = (l >> 5) * 64;
      float acc = 0.f;
#pragma unroll
      for (int d = 0; d < 64; ++d)
        acc += Crow[r * 164 + dh + d] * pr[c * 129 + dh + d];
      acc += __shfl_xor(acc, 32);
      float sm = acc;
      for (int o = 16; o; o >>= 1) sm = fmaxf(sm, __shfl_xor(sm, o));
      const float ee = __expf(acc - sm);
      float s2 = ee;
      for (int o = 16; o; o >>= 1) s2 += __shfl_xor(s2, o);
      if (l < 32) out[O4 + (size_t)grow * 32 + l] = ee / s2;
    }
  } else if (w < 4) {
    for (int r = w; r < 16; r += 4) {
      const int grow = m0 + r;
      const float* cr = Crow + r * 164;
      float v0 = cr[l], v1 = cr[64 + l];
      float ss = v0 * v0 + v1 * v1;
      for (int o = 32; o; o >>= 1) ss += __shfl_xor(ss, o);
      const float den = fmaxf(sqrtf(ss), 1e-12f);
      v0 /= den; v1 /= den;
      out[O1 + (size_t)(4096 + grow) * 128 + l] = v0;
      out[O1 + (size_t)(4096 + grow) * 128 + 64 + l] = v1;
      out[O6 + (size_t)grow * 128 + l] = v0;
      out[O6 + (size_t)grow * 128 + 64 + l] = v1;
    }
  }
}

// ---------------------------------------------------------------------------
// proto_up: per-class EMA scan as weighted sum (order-faithful). 32 x 256.
// ---------------------------------------------------------------------------
__global__ __launch_bounds__(256) void proto_up(
    const int* __restrict__ labels, const float* __restrict__ protos,
    float* __restrict__ out) {
  __shared__ int lab[4096];   // reused as float weights after append
  __shared__ int list[4096];
  __shared__ int wtot[4];
  __shared__ float red[2];
  const int c = blockIdx.x;
  const int t = threadIdx.x;
  const int w = t >> 6, l = t & 63;
  for (int i = t; i < 4096; i += 256) lab[i] = labels[i];
  __syncthreads();
  int cn = 0;
#pragma unroll
  for (int j = 0; j < 16; ++j) {
    const int jj = (j + t) & 15;  // stagger: 2-way LDS aliasing only
    cn += (lab[t * 16 + jj] == c) ? 1 : 0;
  }
  int inc = cn;
  for (int o = 1; o < 64; o <<= 1) {
    const int n = __shfl_up(inc, o);
    if (l >= o) inc += n;
  }
  if (l == 63) wtot[w] = inc;
  __syncthreads();
  int base = 0;
  for (int ww = 0; ww < w; ++ww) base += wtot[ww];
  const int k = wtot[0] + wtot[1] + wtot[2] + wtot[3];
  int off = base + inc - cn;
  for (int j = 0; j < 16; ++j) {  // in-order append (order matters)
    const int i = t * 16 + j;
    if (lab[i] == c) list[off++] = i;
  }
  __syncthreads();
  float* wf = (float*)lab;  // lab dead from here
  for (int j = t; j < k; j += 256)
    wf[j] = 0.01f * __powf(0.99f, (float)(k - 1 - j));
  __syncthreads();
  float acc = 0.f;
  if (t < 128) {
    const float* qfeat = out + O1;
    float a0 = protos[(size_t)c * 128 + t] * __powf(0.99f, (float)k);
    float a1 = 0.f, a2 = 0.f, a3 = 0.f;
    int j = 0;
    for (; j + 4 <= k; j += 4) {  // 4 independent chains
      a0 += wf[j]     * qfeat[(size_t)list[j] * 128 + t];
      a1 += wf[j + 1] * qfeat[(size_t)list[j + 1] * 128 + t];
      a2 += wf[j + 2] * qfeat[(size_t)list[j + 2] * 128 + t];
      a3 += wf[j + 3] * qfeat[(size_t)list[j + 3] * 128 + t];
    }
    for (; j < k; ++j) a0 += wf[j] * qfeat[(size_t)list[j] * 128 + t];
    acc = (a0 + a1) + (a2 + a3);
    float ss = acc * acc;
    for (int o = 32; o; o >>= 1) ss += __shfl_xor(ss, o);
    if ((t & 63) == 0) red[t >> 6] = ss;
  }
  __syncthreads();
  if (t < 128)
    out[O5 + (size_t)c * 128 + t] = acc / fmaxf(sqrtf(red[0] + red[1]), 1e-12f);
}

// ---------------------------------------------------------------------------
extern "C" void kernel_launch(void* const* d_in, const int* in_sizes, int n_in,
                              void* d_out, int out_size, void* d_ws, size_t ws_size,
                              hipStream_t stream) {
  const float* img_q    = (const float*)d_in[0];
  const float* im_k     = (const float*)d_in[1];
  const float* partialY = (const float*)d_in[2];
  const float* W_cls_q  = (const float*)d_in[3];
  const float* b_cls_q  = (const float*)d_in[4];
  const float* W_proj_q = (const float*)d_in[5];
  // d_in[6]=W_cls_k, d_in[7]=b_cls_k dead (key logits discarded)
  const float* W_proj_k = (const float*)d_in[8];
  const float* protos   = (const float*)d_in[9];
  const float* queue    = (const float*)d_in[10];
  const float* queue_ps = (const float*)d_in[11];
  const float* queue_pt = (const float*)d_in[12];
  float* out = (float*)d_out;

  // workspace: wt_q bf16[160][1024] | wt_pk bf16[128][1024] | labels int[4096]
  unsigned short* wt_q  = (unsigned short*)d_ws;
  unsigned short* wt_pk = wt_q + 160 * 1024;
  int* labels = (int*)(wt_pk + 128 * 1024);

  prep<<<288, 256, 0, stream>>>(W_proj_q, W_cls_q, W_proj_k, wt_q, wt_pk);
  mega<<<3584, 320, 0, stream>>>(img_q, im_k, wt_q, wt_pk, b_cls_q, partialY,
                                 protos, queue, queue_ps, queue_pt, out,
                                 labels);
  proto_up<<<32, 256, 0, stream>>>(labels, protos, out);
}

// Round 7
// 232.711 us; speedup vs baseline: 1.0297x; 1.0297x over previous
//
#include <hip/hip_runtime.h>
#include <hip/hip_bf16.h>
#include <stdint.h>

// ---------------------------------------------------------------------------
// PiCO forward: B=4096, D_IN=1024, LOW_DIM=128, NUM_CLASS=32, MOCO_QUEUE=65536
// Round 7: weight tensor pre-packed in MFMA-fragment stream order so the
// barrier-free K-loop's B reads are contiguous 1KB-per-wave-instruction
// (was 16x64B at 2KB stride -> L1-alias + channel-conflict serialized).
// A-stage also made 1KB-contiguous. Everything else = R6 (passing).
// ---------------------------------------------------------------------------

typedef __attribute__((ext_vector_type(8))) short bf16x8;
typedef __attribute__((ext_vector_type(4))) float f32x4;

// output offsets (in floats), concatenated in reference return order
constexpr size_t O0 = 0;          // output            (4096,32)
constexpr size_t O1 = 131072;     // features          (73728,128)
constexpr size_t O2 = 9568256;    // pseudo_scores     (73728,32)
constexpr size_t O3 = 11927552;   // partial_target    (73728,32)
constexpr size_t O4 = 14286848;   // score_prot        (4096,32)
constexpr size_t O5 = 14417920;   // new_protos        (32,128)
constexpr size_t O6 = 14422016;   // new_queue         (65536,128)
constexpr size_t O7 = 22810624;   // new_queue_pseudo  (65536,32)
constexpr size_t O8 = 24907776;   // new_queue_partial (65536,32)

__device__ __forceinline__ unsigned short f2b(float x) {
  union { float f; uint32_t u; } v; v.f = x;
  uint32_t u = v.u;
  uint32_t r = (u + 0x7fffu + ((u >> 16) & 1u)) >> 16;   // RNE f32->bf16
  return (unsigned short)r;
}

// ---------------------------------------------------------------------------
// prep: weight transposes into FRAGMENT-ORDER bf16 buffers.
// Chunk (s, kk) = 1024 bf16 (2KB) contiguous:
//   [0:512)   = b0 frags: lane l -> row (s*32 + (l&15)),    k = kk*32+(l>>4)*8..+7
//   [512:1024)= b1 frags: lane l -> row (s*32 + 16+(l&15)), same k
// wt_q: strips 0-4 (proj rows 0-127 = s0-3, cls rows = s4). wt_pk: strips 0-3.
//  bid [0,128)   : W_proj_q   -> wt_q chunks (s=bid>>5, kk=bid&31)
//  bid [128,160) : W_cls_q    -> wt_q chunks (s=4, kk=bid-128)
//  bid [160,288) : .999Wpk+.001Wpq -> wt_pk chunks (s=(bid-160)>>5, kk=&31)
// ---------------------------------------------------------------------------
__global__ __launch_bounds__(256) void prep(
    const float* __restrict__ Wpq, const float* __restrict__ Wcq,
    const float* __restrict__ Wpk,
    unsigned short* __restrict__ wt_q, unsigned short* __restrict__ wt_pk) {
  const int bid = blockIdx.x;
  const int t = threadIdx.x;
  const float *W1, *W2 = nullptr;
  float a1 = 1.f, a2 = 0.f;
  unsigned short* dst;
  int kb, nbr, s, N;
  if (bid < 128) {
    W1 = Wpq; N = 128; kb = (bid & 31) * 32; nbr = (bid >> 5) * 32;
    s = bid >> 5; dst = wt_q;
  } else if (bid < 160) {
    W1 = Wcq; N = 32; kb = (bid - 128) * 32; nbr = 0; s = 4; dst = wt_q;
  } else {
    W1 = Wpk; W2 = Wpq; a1 = 0.999f; a2 = 0.001f; N = 128;
    const int b = bid - 160; kb = (b & 31) * 32; nbr = (b >> 5) * 32;
    s = b >> 5; dst = wt_pk;
  }
  const int kk = (bid < 128) ? (bid & 31) : (bid < 160 ? bid - 128 : ((bid - 160) & 31));
  __shared__ float tile[32][33];   // tile[k_local][n_local]
  const int tx = t & 31, ty = t >> 5;
#pragma unroll
  for (int j = 0; j < 4; ++j) {
    const int k = kb + ty + 8 * j;
    float v = W1[(size_t)k * N + nbr + tx] * a1;
    if (W2) v += W2[(size_t)k * N + nbr + tx] * a2;
    tile[ty + 8 * j][tx] = v;
  }
  __syncthreads();
  // fragment write: thread t emits 4 consecutive bf16 (8B) of the 2KB chunk
  const int lf = (t >> 1) & 63;          // lane within the consuming wave
  const int half = t >> 7;               // 0 = b0 block, 1 = b1 block
  const int e0 = (t & 1) * 4;            // k-element quad within the frag
  const int nloc = half * 16 + (lf & 15);
  const int kloc = ((lf >> 4) << 3) + e0;
  uint2 pk;
  pk.x = (uint32_t)f2b(tile[kloc][nloc]) | ((uint32_t)f2b(tile[kloc + 1][nloc]) << 16);
  pk.y = (uint32_t)f2b(tile[kloc + 2][nloc]) | ((uint32_t)f2b(tile[kloc + 3][nloc]) << 16);
  *(uint2*)(dst + (size_t)(s * 32 + kk) * 1024 + t * 4) = pk;
}

// ---------------------------------------------------------------------------
// mega: 3584 blocks x 320 threads.
//  bid [0,256)     : q-path GEMM (BM=16 x BN=160) + full q epilogue
//  bid [256,512)   : k-path GEMM (BM=16 x BN=128) + l2norm epilogue
//  bid [512,3584)  : queue copies (grid-stride, BW-bound)
// ---------------------------------------------------------------------------
__global__ __launch_bounds__(320) void mega(
    const float* __restrict__ img_q, const float* __restrict__ im_k,
    const unsigned short* __restrict__ wt_q,
    const unsigned short* __restrict__ wt_pk,
    const float* __restrict__ bias, const float* __restrict__ partialY,
    const float* __restrict__ protos, const float* __restrict__ queue,
    const float* __restrict__ qp, const float* __restrict__ qpt,
    float* __restrict__ out, int* __restrict__ labels) {
  __shared__ __align__(16) unsigned char smem[32768];
  const int bid = blockIdx.x;
  const int t = threadIdx.x;

  if (bid >= 512) {  // ---- copy path: 141 MB of queue concat + requeue ----
    constexpr long NQ4 = (long)65536 * 128 / 4;   // 2097152
    constexpr long NP4 = (long)65536 * 32 / 4;    // 524288
    constexpr long TOT = NQ4 + 2 * NP4;           // 3145728
    float4* o4 = (float4*)out;
    for (long idx = (long)(bid - 512) * 320 + t; idx < TOT; idx += 3072L * 320) {
      if (idx < NQ4) {
        const float4 v = ((const float4*)queue)[idx];
        o4[O1 / 4 + (2L * 4096 * 128) / 4 + idx] = v;
        if ((idx >> 5) >= 4096) o4[O6 / 4 + idx] = v;
      } else if (idx < NQ4 + NP4) {
        const long i = idx - NQ4;
        const float4 v = ((const float4*)qp)[i];
        o4[O2 / 4 + (2L * 4096 * 32) / 4 + i] = v;
        if ((i >> 3) >= 4096) o4[O7 / 4 + i] = v;
      } else {
        const long i = idx - NQ4 - NP4;
        const float4 v = ((const float4*)qpt)[i];
        o4[O3 / 4 + (2L * 4096 * 32) / 4 + i] = v;
        if ((i >> 3) >= 4096) o4[O8 / 4 + i] = v;
      }
    }
    return;
  }

  // ---- GEMM paths ----
  const int w = t >> 6, l = t & 63;
  const int ar = l & 15, kg = l >> 4;
  const bool isq = bid < 256;
  const int m0 = (isq ? bid : bid - 256) * 16;
  const float* A = isq ? img_q : im_k;
  const unsigned short* Wt = isq ? wt_q : wt_pk;
  const int nstrips = isq ? 5 : 4;

  // stage A once: 16 rows x 1024 f32 -> bf16 LDS, XOR-swizzled.
  // Per instruction a wave reads 1KB CONTIGUOUS (row-major quarter-rows).
  if (t < 256) {
    const int w4 = t >> 6, l6 = t & 63;
#pragma unroll
    for (int j = 0; j < 16; ++j) {
      const int r = w4 * 4 + (j >> 2);
      const int col = (j & 3) * 256 + l6 * 4;   // f32 element
      const float4 v = *(const float4*)(A + (size_t)(m0 + r) * 1024 + col);
      uint2 pk;
      pk.x = (uint32_t)f2b(v.x) | ((uint32_t)f2b(v.y) << 16);
      pk.y = (uint32_t)f2b(v.z) | ((uint32_t)f2b(v.w) << 16);
      *(uint2*)(smem + r * 2048 + ((col * 2) ^ ((r & 7) << 4))) = pk;
    }
  }
  __syncthreads();

  // barrier-free K-loop: A from LDS, B streamed contiguously from the
  // fragment-ordered weight buffer (1KB/wave-instruction, sequential).
  f32x4 acc0 = {0.f, 0.f, 0.f, 0.f}, acc1 = {0.f, 0.f, 0.f, 0.f};
  if (w < nstrips) {
    const unsigned short* bp = Wt + (size_t)(w * 32) * 1024 + l * 8;
    const int abase = ar * 2048;
    const int asw = (ar & 7) << 4;
#pragma unroll 8
    for (int kk = 0; kk < 32; ++kk) {
      const int k0 = kk * 32 + kg * 8;
      bf16x8 a = *(const bf16x8*)(smem + abase + ((k0 * 2) ^ asw));
      bf16x8 b0 = *(const bf16x8*)(bp + (size_t)kk * 1024);
      bf16x8 b1 = *(const bf16x8*)(bp + (size_t)kk * 1024 + 512);
      acc0 = __builtin_amdgcn_mfma_f32_16x16x32_bf16(a, b0, acc0, 0, 0, 0);
      acc1 = __builtin_amdgcn_mfma_f32_16x16x32_bf16(a, b1, acc1, 0, 0, 0);
    }
  }
  __syncthreads();  // all waves done reading sA; safe to overlay pr/Crow

  // epilogue: acc -> LDS row buffer; protos -> LDS (q only)
  float* pr = (float*)smem;                   // 32*129 f32 = 16504 B
  float* Crow = (float*)(smem + 16512);       // 16 x 164 f32 = 10496 B
  if (w < nstrips) {
#pragma unroll
    for (int j = 0; j < 4; ++j) {
      Crow[(kg * 4 + j) * 164 + w * 32 + ar] = acc0[j];
      Crow[(kg * 4 + j) * 164 + w * 32 + 16 + ar] = acc1[j];
    }
  }
  if (isq) {
    for (int i = t; i < 4096; i += 320)
      pr[(i >> 7) * 129 + (i & 127)] = protos[i];
  }
  __syncthreads();

  if (isq) {
    for (int r = w; r < 16; r += 5) {
      const int grow = m0 + r;
      const float* cr = Crow + r * 164;
      // logits + bias -> softmax -> * partial_Y
      float logit = -1e30f;
      if (l < 32) logit = cr[128 + l] + bias[l];
      float m = logit;
      for (int o = 32; o; o >>= 1) m = fmaxf(m, __shfl_xor(m, o));
      const float e = (l < 32) ? __expf(logit - m) : 0.f;
      float ssum = e;
      for (int o = 32; o; o >>= 1) ssum += __shfl_xor(ssum, o);
      const float py = (l < 32) ? partialY[(size_t)grow * 32 + l] : 0.f;
      const float p = e / ssum * py;
      if (l < 32) {
        out[O0 + (size_t)grow * 32 + l] = logit;
        out[O2 + (size_t)grow * 32 + l] = p;
        out[O2 + (size_t)(4096 + grow) * 32 + l] = p;
        out[O7 + (size_t)grow * 32 + l] = p;
        out[O3 + (size_t)grow * 32 + l] = py;
        out[O3 + (size_t)(4096 + grow) * 32 + l] = py;
        out[O8 + (size_t)grow * 32 + l] = py;
      }
      // argmax (first-index-wins)
      float av = (l < 32) ? p : -1.f;
      int ai = (l < 32) ? l : 1000;
      for (int o = 32; o; o >>= 1) {
        const float ov = __shfl_xor(av, o);
        const int oi = __shfl_xor(ai, o);
        if (ov > av || (ov == av && oi < ai)) { av = ov; ai = oi; }
      }
      if (l == 0) labels[grow] = ai;
      // l2norm(q) -> features + normalized row back to LDS (same wave)
      float v0 = cr[l], v1 = cr[64 + l];
      float ss = v0 * v0 + v1 * v1;
      for (int o = 32; o; o >>= 1) ss += __shfl_xor(ss, o);
      const float den = fmaxf(sqrtf(ss), 1e-12f);
      v0 /= den; v1 /= den;
      out[O1 + (size_t)grow * 128 + l] = v0;
      out[O1 + (size_t)grow * 128 + 64 + l] = v1;
      Crow[r * 164 + l] = v0;
      Crow[r * 164 + 64 + l] = v1;   // same-wave LDS RAW: lockstep-safe
      // score_prot = softmax(qn @ protos^T): lane pair (l,l+32), class l&31
      const int c = l & 31;
      const int dh = (l >> 5) * 64;
      float acc = 0.f;
#pragma unroll
      for (int d = 0; d < 64; ++d)
        acc += Crow[r * 164 + dh + d] * pr[c * 129 + dh + d];
      acc += __shfl_xor(acc, 32);
      float sm = acc;
      for (int o = 16; o; o >>= 1) sm = fmaxf(sm, __shfl_xor(sm, o));
      const float ee = __expf(acc - sm);
      float s2 = ee;
      for (int o = 16; o; o >>= 1) s2 += __shfl_xor(s2, o);
      if (l < 32) out[O4 + (size_t)grow * 32 + l] = ee / s2;
    }
  } else if (w < 4) {
    for (int r = w; r < 16; r += 4) {
      const int grow = m0 + r;
      const float* cr = Crow + r * 164;
      float v0 = cr[l], v1 = cr[64 + l];
      float ss = v0 * v0 + v1 * v1;
      for (int o = 32; o; o >>= 1) ss += __shfl_xor(ss, o);
      const float den = fmaxf(sqrtf(ss), 1e-12f);
      v0 /= den; v1 /= den;
      out[O1 + (size_t)(4096 + grow) * 128 + l] = v0;
      out[O1 + (size_t)(4096 + grow) * 128 + 64 + l] = v1;
      out[O6 + (size_t)grow * 128 + l] = v0;
      out[O6 + (size_t)grow * 128 + 64 + l] = v1;
    }
  }
}

// ---------------------------------------------------------------------------
// proto_up: per-class EMA scan as weighted sum (order-faithful). 32 x 256.
// ---------------------------------------------------------------------------
__global__ __launch_bounds__(256) void proto_up(
    const int* __restrict__ labels, const float* __restrict__ protos,
    float* __restrict__ out) {
  __shared__ int lab[4096];   // reused as float weights after append
  __shared__ int list[4096];
  __shared__ int wtot[4];
  __shared__ float red[2];
  const int c = blockIdx.x;
  const int t = threadIdx.x;
  const int w = t >> 6, l = t & 63;
  for (int i = t; i < 4096; i += 256) lab[i] = labels[i];
  __syncthreads();
  int cn = 0;
#pragma unroll
  for (int j = 0; j < 16; ++j) {
    const int jj = (j + t) & 15;  // stagger: 2-way LDS aliasing only
    cn += (lab[t * 16 + jj] == c) ? 1 : 0;
  }
  int inc = cn;
  for (int o = 1; o < 64; o <<= 1) {
    const int n = __shfl_up(inc, o);
    if (l >= o) inc += n;
  }
  if (l == 63) wtot[w] = inc;
  __syncthreads();
  int base = 0;
  for (int ww = 0; ww < w; ++ww) base += wtot[ww];
  const int k = wtot[0] + wtot[1] + wtot[2] + wtot[3];
  int off = base + inc - cn;
  for (int j = 0; j < 16; ++j) {  // in-order append (order matters)
    const int i = t * 16 + j;
    if (lab[i] == c) list[off++] = i;
  }
  __syncthreads();
  float* wf = (float*)lab;  // lab dead from here
  for (int j = t; j < k; j += 256)
    wf[j] = 0.01f * __powf(0.99f, (float)(k - 1 - j));
  __syncthreads();
  float acc = 0.f;
  if (t < 128) {
    const float* qfeat = out + O1;
    float a0 = protos[(size_t)c * 128 + t] * __powf(0.99f, (float)k);
    float a1 = 0.f, a2 = 0.f, a3 = 0.f;
    int j = 0;
    for (; j + 4 <= k; j += 4) {  // 4 independent chains
      a0 += wf[j]     * qfeat[(size_t)list[j] * 128 + t];
      a1 += wf[j + 1] * qfeat[(size_t)list[j + 1] * 128 + t];
      a2 += wf[j + 2] * qfeat[(size_t)list[j + 2] * 128 + t];
      a3 += wf[j + 3] * qfeat[(size_t)list[j + 3] * 128 + t];
    }
    for (; j < k; ++j) a0 += wf[j] * qfeat[(size_t)list[j] * 128 + t];
    acc = (a0 + a1) + (a2 + a3);
    float ss = acc * acc;
    for (int o = 32; o; o >>= 1) ss += __shfl_xor(ss, o);
    if ((t & 63) == 0) red[t >> 6] = ss;
  }
  __syncthreads();
  if (t < 128)
    out[O5 + (size_t)c * 128 + t] = acc / fmaxf(sqrtf(red[0] + red[1]), 1e-12f);
}

// ---------------------------------------------------------------------------
extern "C" void kernel_launch(void* const* d_in, const int* in_sizes, int n_in,
                              void* d_out, int out_size, void* d_ws, size_t ws_size,
                              hipStream_t stream) {
  const float* img_q    = (const float*)d_in[0];
  const float* im_k     = (const float*)d_in[1];
  const float* partialY = (const float*)d_in[2];
  const float* W_cls_q  = (const float*)d_in[3];
  const float* b_cls_q  = (const float*)d_in[4];
  const float* W_proj_q = (const float*)d_in[5];
  // d_in[6]=W_cls_k, d_in[7]=b_cls_k dead (key logits discarded)
  const float* W_proj_k = (const float*)d_in[8];
  const float* protos   = (const float*)d_in[9];
  const float* queue    = (const float*)d_in[10];
  const float* queue_ps = (const float*)d_in[11];
  const float* queue_pt = (const float*)d_in[12];
  float* out = (float*)d_out;

  // workspace: wt_q frag bf16[5*32*1024] | wt_pk frag bf16[4*32*1024] | labels
  unsigned short* wt_q  = (unsigned short*)d_ws;
  unsigned short* wt_pk = wt_q + 5 * 32 * 1024;
  int* labels = (int*)(wt_pk + 4 * 32 * 1024);

  prep<<<288, 256, 0, stream>>>(W_proj_q, W_cls_q, W_proj_k, wt_q, wt_pk);
  mega<<<3584, 320, 0, stream>>>(img_q, im_k, wt_q, wt_pk, b_cls_q, partialY,
                                 protos, queue, queue_ps, queue_pt, out,
                                 labels);
  proto_up<<<32, 256, 0, stream>>>(labels, protos, out);
}